// Round 3
// baseline (1134.364 us; speedup 1.0000x reference)
//
#include <hip/hip_runtime.h>

// VariationalLSTM: B=65536, T=24, H=64. 1024 WGs x 256 thr (4 waves), 4 row-blocks
// of 16 rows per WG. Wave w owns gate units u = 16w + (lane&15) for all 4 gates.
// R1-proven LDS layout: bf16 tiles [16 rows m][64 units u], XOR swizzle
// byte ^= (m&7)<<4; A-frags via ds_read_b128, k-map f(kk,hi,e)=32kk+8hi+e shared
// by A and B. Double-buffered tiles -> ONE barrier per timestep. cvt_pk writes.

typedef short short8v __attribute__((ext_vector_type(8)));
typedef float f32x4 __attribute__((ext_vector_type(4)));

#define LOG2E 1.44269504088896340736f

__device__ inline float fsig(float x){
  float e = __builtin_amdgcn_exp2f(-LOG2E * x);
  return __builtin_amdgcn_rcpf(1.0f + e);
}
__device__ inline float ftanh(float x){
  float e = __builtin_amdgcn_exp2f((2.0f * LOG2E) * x);
  return 1.0f - 2.0f * __builtin_amdgcn_rcpf(1.0f + e);
}
__device__ inline unsigned short bf16c(float f){  // RNE f32->bf16 (weight init only)
  unsigned uu = __builtin_bit_cast(unsigned, f);
  uu = (uu + 0x7fffu + ((uu >> 16) & 1u)) >> 16;
  return (unsigned short)uu;
}

// 4 rows (same unit column u) -> 2x v_cvt_pk_bf16_f32 (D.lo=S0 per T12) + 4x b16.
#define PK_STORE4(T, I, f0, f1, f2, f3) do{                       \
    unsigned _w01, _w23;                                          \
    asm("v_cvt_pk_bf16_f32 %0, %1, %2" : "=v"(_w01) : "v"(f0), "v"(f1)); \
    asm("v_cvt_pk_bf16_f32 %0, %1, %2" : "=v"(_w23) : "v"(f2), "v"(f3)); \
    (T)[(I)[0]] = (unsigned short)_w01;                           \
    (T)[(I)[1]] = (unsigned short)(_w01 >> 16);                   \
    (T)[(I)[2]] = (unsigned short)_w23;                           \
    (T)[(I)[3]] = (unsigned short)(_w23 >> 16);                   \
  }while(0)

__global__ __launch_bounds__(256, 4) void vlstm_kernel(
    const float* __restrict__ x,
    const float* __restrict__ Wih1, const float* __restrict__ Whh1,
    const float* __restrict__ bih1, const float* __restrict__ bhh1,
    const float* __restrict__ Wih2, const float* __restrict__ Whh2,
    const float* __restrict__ bih2, const float* __restrict__ bhh2,
    const float* __restrict__ Wout, const float* __restrict__ bout,
    const float* __restrict__ h10, const float* __restrict__ c10,
    const float* __restrict__ h20, const float* __restrict__ c20,
    const float* __restrict__ mt1v, const float* __restrict__ mt2v,
    const float* __restrict__ ml1v, const float* __restrict__ ml2v,
    float* __restrict__ out)
{
  __shared__ unsigned short sh1L[2][1024];  // h1*m_layer1           (layer2 input)
  __shared__ unsigned short sh1T[2][1024];  // h1*m_layer1*m_time1   (next-step L1 h)
  __shared__ unsigned short sh2T[2][1024];  // h2*m_layer2*m_time2   (next-step L2 h)
  __shared__ float h2f[1024];               // final h2 (fp32)
  __shared__ float xlds[384];               // x transposed [24][16]

  const int tid = threadIdx.x;
  const int w  = tid >> 6;
  const int l  = tid & 63;
  const int hi = l >> 4;
  const int lo = l & 15;
  const int u  = 16 * w + lo;               // gate unit owned (D col = lane&15)

  // ---- one-time: biases, x-coeffs, weight B-fragments (k-map 32kk+8hi+e) ----
  float b1v[4], b2v[4], wiv[4];
  short8v fr1[4][2], frI[4][2], frH[4][2];
#pragma unroll
  for (int j = 0; j < 4; ++j){
    int n = u + 64 * j;
    b1v[j] = bih1[n] + bhh1[n];
    b2v[j] = bih2[n] + bhh2[n];
    wiv[j] = Wih1[n];
#pragma unroll
    for (int kk = 0; kk < 2; ++kk){
      int off = n * 64 + 32 * kk + 8 * hi;
      short8v s;
#pragma unroll
      for (int e = 0; e < 8; ++e) s[e] = (short)bf16c(Whh1[off + e]);
      fr1[j][kk] = s;
#pragma unroll
      for (int e = 0; e < 8; ++e) s[e] = (short)bf16c(Wih2[off + e]);
      frI[j][kk] = s;
#pragma unroll
      for (int e = 0; e < 8; ++e) s[e] = (short)bf16c(Whh2[off + e]);
      frH[j][kk] = s;
    }
  }

  // ---- swizzled LDS offsets (ushort indices), byte ^= (m&7)<<4 ----
  int wIdx[4];                 // writes: rows m = 4hi+r, col u
#pragma unroll
  for (int r = 0; r < 4; ++r){
    int m = 4 * hi + r;
    wIdx[r] = ((m * 128 + u * 2) ^ ((m & 7) << 4)) >> 1;
  }
  int rIdx[2];                 // A-frag b128 reads: m = lo, k = 32kk + 8hi + e
#pragma unroll
  for (int kk = 0; kk < 2; ++kk){
    rIdx[kk] = ((lo * 128 + kk * 64 + hi * 16) ^ ((lo & 7) << 4)) >> 1;
  }

#pragma unroll 1
  for (int blk = 0; blk < 4; ++blk){
    const int row0 = blockIdx.x * 64 + blk * 16;

    for (int idx = tid; idx < 384; idx += 256){
      int r = idx / 24, tt = idx - r * 24;
      xlds[tt * 16 + r] = x[(row0 + r) * 24 + tt];
    }
    float c1r[4], c2r[4], ml1r[4], ml2r[4], mt1r[4], mt2r[4];
    float h1i[4], h2i[4];
#pragma unroll
    for (int r = 0; r < 4; ++r){
      int gofs = (row0 + 4 * hi + r) * 64 + u;
      c1r[r]  = c10[gofs];  c2r[r]  = c20[gofs];
      ml1r[r] = ml1v[gofs]; ml2r[r] = ml2v[gofs];
      mt1r[r] = mt1v[gofs]; mt2r[r] = mt2v[gofs];
      h1i[r] = h10[gofs] * mt1r[r];
      h2i[r] = h20[gofs] * mt2r[r];
    }
    PK_STORE4(sh1T[0], wIdx, h1i[0], h1i[1], h1i[2], h1i[3]);
    PK_STORE4(sh2T[0], wIdx, h2i[0], h2i[1], h2i[2], h2i[3]);
    __syncthreads();

    short8v a1[2], at2[2];
    a1[0] = *(const short8v*)&sh1T[0][rIdx[0]];
    a1[1] = *(const short8v*)&sh1T[0][rIdx[1]];

    int P = 0;
#pragma unroll 1
    for (int t = 0; t < 24; ++t){
      const int Q = P ^ 1;
      f32x4 xv = *(const f32x4*)&xlds[t * 16 + 4 * hi];

      // ---- layer 1 (reads a1 = h1T[P], preloaded) ----
      f32x4 gt[4];
#pragma unroll
      for (int j = 0; j < 4; ++j){
        f32x4 acc;
#pragma unroll
        for (int r = 0; r < 4; ++r) acc[r] = fmaf(xv[r], wiv[j], b1v[j]);
        acc = __builtin_amdgcn_mfma_f32_16x16x32_bf16(a1[0], fr1[j][0], acc, 0, 0, 0);
        acc = __builtin_amdgcn_mfma_f32_16x16x32_bf16(a1[1], fr1[j][1], acc, 0, 0, 0);
        gt[j] = acc;
      }
      float h1l[4], h1t[4];
#pragma unroll
      for (int r = 0; r < 4; ++r){
        float ti = fsig(gt[0][r]);
        float tf = fsig(gt[1][r]);
        float tg = ftanh(gt[2][r]);
        float to = fsig(gt[3][r]);
        float cn = fmaf(tf, c1r[r], ti * tg);
        c1r[r] = cn;
        h1l[r] = to * ftanh(cn) * ml1r[r];
        h1t[r] = h1l[r] * mt1r[r];
      }
      PK_STORE4(sh1L[Q], wIdx, h1l[0], h1l[1], h1l[2], h1l[3]);
      PK_STORE4(sh1T[Q], wIdx, h1t[0], h1t[1], h1t[2], h1t[3]);

      __syncthreads();   // the ONLY barrier per step

      short8v a2[2];
      a2[0]  = *(const short8v*)&sh1L[Q][rIdx[0]];
      a2[1]  = *(const short8v*)&sh1L[Q][rIdx[1]];
      a1[0]  = *(const short8v*)&sh1T[Q][rIdx[0]];   // next step's layer-1 input
      a1[1]  = *(const short8v*)&sh1T[Q][rIdx[1]];
      at2[0] = *(const short8v*)&sh2T[P][rIdx[0]];   // h2T written at t-1 (or init)
      at2[1] = *(const short8v*)&sh2T[P][rIdx[1]];

      // ---- layer 2 ----
#pragma unroll
      for (int j = 0; j < 4; ++j){
        f32x4 acc;
#pragma unroll
        for (int r = 0; r < 4; ++r) acc[r] = b2v[j];
        acc = __builtin_amdgcn_mfma_f32_16x16x32_bf16(a2[0],  frI[j][0], acc, 0, 0, 0);
        acc = __builtin_amdgcn_mfma_f32_16x16x32_bf16(a2[1],  frI[j][1], acc, 0, 0, 0);
        acc = __builtin_amdgcn_mfma_f32_16x16x32_bf16(at2[0], frH[j][0], acc, 0, 0, 0);
        acc = __builtin_amdgcn_mfma_f32_16x16x32_bf16(at2[1], frH[j][1], acc, 0, 0, 0);
        gt[j] = acc;
      }
      float h2t[4];
#pragma unroll
      for (int r = 0; r < 4; ++r){
        float ti = fsig(gt[0][r]);
        float tf = fsig(gt[1][r]);
        float tg = ftanh(gt[2][r]);
        float to = fsig(gt[3][r]);
        float cn = fmaf(tf, c2r[r], ti * tg);
        c2r[r] = cn;
        float h2l = to * ftanh(cn) * ml2r[r];
        h2t[r] = h2l * mt2r[r];
        if (t == 23) h2f[(4 * hi + r) * 64 + u] = h2l;
      }
      PK_STORE4(sh2T[Q], wIdx, h2t[0], h2t[1], h2t[2], h2t[3]);  // post-barrier write

      P = Q;
    }
    __syncthreads();   // h2f visible to reducer

    // ---- output: out[row][o] = sum_u h2f[row][u]*Wout[o][u] + bout[o] ----
    if (tid < 32){
      int r = tid & 15, o = tid >> 4;
      float acc = bout[o];
#pragma unroll 8
      for (int uu = 0; uu < 64; ++uu)
        acc = fmaf(h2f[r * 64 + uu], Wout[o * 64 + uu], acc);
      out[(row0 + r) * 2 + o] = acc;
    }
    __syncthreads();   // protect all tiles before next block's init writes
  }
}

extern "C" void kernel_launch(void* const* d_in, const int* in_sizes, int n_in,
                              void* d_out, int out_size, void* d_ws, size_t ws_size,
                              hipStream_t stream)
{
  vlstm_kernel<<<dim3(1024), dim3(256), 0, stream>>>(
      (const float*)d_in[0],  (const float*)d_in[1],  (const float*)d_in[2],
      (const float*)d_in[3],  (const float*)d_in[4],  (const float*)d_in[5],
      (const float*)d_in[6],  (const float*)d_in[7],  (const float*)d_in[8],
      (const float*)d_in[9],  (const float*)d_in[10], (const float*)d_in[11],
      (const float*)d_in[12], (const float*)d_in[13], (const float*)d_in[14],
      (const float*)d_in[15], (const float*)d_in[16], (const float*)d_in[17],
      (const float*)d_in[18], (float*)d_out);
}

// Round 4
// 842.094 us; speedup vs baseline: 1.3471x; 1.3471x over previous
//
#include <hip/hip_runtime.h>

// VariationalLSTM: B=65536, T=24, H=64. 4096 WGs x 256 thr (4 waves); each WG owns
// ONE 16-row batch tile for all 24 steps. Wave w owns gate units u = 16w + (lane&15).
// R1-proven LDS layout: bf16 tiles [16 rows m][64 units u], XOR swizzle
// byte ^= (m&7)<<4; A-frags via ds_read_b128, k-map f(kk,hi,e)=32kk+8hi+e shared
// by A and B. Double-buffered tiles -> ONE barrier per timestep. cvt_pk stores.
// __launch_bounds__(256,3): VGPR budget ~168 >= ~140 needed -> weights stay
// register-resident (the (256,4) cap at 128 spilled them: 4 GB scratch traffic, R3).

typedef short short8v __attribute__((ext_vector_type(8)));
typedef float f32x4 __attribute__((ext_vector_type(4)));

#define LOG2E 1.44269504088896340736f

__device__ inline float fsig(float x){
  float e = __builtin_amdgcn_exp2f(-LOG2E * x);
  return __builtin_amdgcn_rcpf(1.0f + e);
}
__device__ inline float ftanh(float x){
  float e = __builtin_amdgcn_exp2f((2.0f * LOG2E) * x);
  return 1.0f - 2.0f * __builtin_amdgcn_rcpf(1.0f + e);
}
__device__ inline unsigned short bf16c(float f){  // RNE f32->bf16 (weight init only)
  unsigned uu = __builtin_bit_cast(unsigned, f);
  uu = (uu + 0x7fffu + ((uu >> 16) & 1u)) >> 16;
  return (unsigned short)uu;
}

// 4 rows (same unit column u) -> 2x v_cvt_pk_bf16_f32 (D.lo=S0 per T12) + 4x b16.
#define PK_STORE4(T, I, f0, f1, f2, f3) do{                       \
    unsigned _w01, _w23;                                          \
    asm("v_cvt_pk_bf16_f32 %0, %1, %2" : "=v"(_w01) : "v"(f0), "v"(f1)); \
    asm("v_cvt_pk_bf16_f32 %0, %1, %2" : "=v"(_w23) : "v"(f2), "v"(f3)); \
    (T)[(I)[0]] = (unsigned short)_w01;                           \
    (T)[(I)[1]] = (unsigned short)(_w01 >> 16);                   \
    (T)[(I)[2]] = (unsigned short)_w23;                           \
    (T)[(I)[3]] = (unsigned short)(_w23 >> 16);                   \
  }while(0)

__global__ __launch_bounds__(256, 3) void vlstm_kernel(
    const float* __restrict__ x,
    const float* __restrict__ Wih1, const float* __restrict__ Whh1,
    const float* __restrict__ bih1, const float* __restrict__ bhh1,
    const float* __restrict__ Wih2, const float* __restrict__ Whh2,
    const float* __restrict__ bih2, const float* __restrict__ bhh2,
    const float* __restrict__ Wout, const float* __restrict__ bout,
    const float* __restrict__ h10, const float* __restrict__ c10,
    const float* __restrict__ h20, const float* __restrict__ c20,
    const float* __restrict__ mt1v, const float* __restrict__ mt2v,
    const float* __restrict__ ml1v, const float* __restrict__ ml2v,
    float* __restrict__ out)
{
  __shared__ unsigned short sh1L[2][1024];  // h1*m_layer1           (layer2 input)
  __shared__ unsigned short sh1T[2][1024];  // h1*m_layer1*m_time1   (next-step L1 h)
  __shared__ unsigned short sh2T[2][1024];  // h2*m_layer2*m_time2   (next-step L2 h)
  __shared__ float h2f[1024];               // final h2 (fp32)
  __shared__ float xlds[384];               // x transposed [24][16]

  const int tid = threadIdx.x;
  const int w  = tid >> 6;
  const int l  = tid & 63;
  const int hi = l >> 4;
  const int lo = l & 15;
  const int u  = 16 * w + lo;               // gate unit owned (D col = lane&15)

  // ---- one-time: biases, x-coeffs, weight B-fragments (k-map 32kk+8hi+e) ----
  float b1v[4], b2v[4], wiv[4];
  short8v fr1[4][2], frI[4][2], frH[4][2];
#pragma unroll
  for (int j = 0; j < 4; ++j){
    int n = u + 64 * j;
    b1v[j] = bih1[n] + bhh1[n];
    b2v[j] = bih2[n] + bhh2[n];
    wiv[j] = Wih1[n];
#pragma unroll
    for (int kk = 0; kk < 2; ++kk){
      int off = n * 64 + 32 * kk + 8 * hi;
      short8v s;
#pragma unroll
      for (int e = 0; e < 8; ++e) s[e] = (short)bf16c(Whh1[off + e]);
      fr1[j][kk] = s;
#pragma unroll
      for (int e = 0; e < 8; ++e) s[e] = (short)bf16c(Wih2[off + e]);
      frI[j][kk] = s;
#pragma unroll
      for (int e = 0; e < 8; ++e) s[e] = (short)bf16c(Whh2[off + e]);
      frH[j][kk] = s;
    }
  }

  // ---- swizzled LDS offsets (ushort indices), byte ^= (m&7)<<4 ----
  int wIdx[4];                 // writes: rows m = 4hi+r, col u
#pragma unroll
  for (int r = 0; r < 4; ++r){
    int m = 4 * hi + r;
    wIdx[r] = ((m * 128 + u * 2) ^ ((m & 7) << 4)) >> 1;
  }
  int rIdx[2];                 // A-frag b128 reads: m = lo, k = 32kk + 8hi + e
#pragma unroll
  for (int kk = 0; kk < 2; ++kk){
    rIdx[kk] = ((lo * 128 + kk * 64 + hi * 16) ^ ((lo & 7) << 4)) >> 1;
  }

  const int row0 = blockIdx.x * 16;

  for (int idx = tid; idx < 384; idx += 256){
    int r = idx / 24, tt = idx - r * 24;
    xlds[tt * 16 + r] = x[(row0 + r) * 24 + tt];
  }
  float c1r[4], c2r[4], ml1r[4], ml2r[4], mt1r[4], mt2r[4];
  float h1i[4], h2i[4];
#pragma unroll
  for (int r = 0; r < 4; ++r){
    int gofs = (row0 + 4 * hi + r) * 64 + u;
    c1r[r]  = c10[gofs];  c2r[r]  = c20[gofs];
    ml1r[r] = ml1v[gofs]; ml2r[r] = ml2v[gofs];
    mt1r[r] = mt1v[gofs]; mt2r[r] = mt2v[gofs];
    h1i[r] = h10[gofs] * mt1r[r];
    h2i[r] = h20[gofs] * mt2r[r];
  }
  PK_STORE4(sh1T[0], wIdx, h1i[0], h1i[1], h1i[2], h1i[3]);
  PK_STORE4(sh2T[0], wIdx, h2i[0], h2i[1], h2i[2], h2i[3]);
  __syncthreads();

  short8v a1[2], at2[2];
  a1[0] = *(const short8v*)&sh1T[0][rIdx[0]];
  a1[1] = *(const short8v*)&sh1T[0][rIdx[1]];

  int P = 0;
#pragma unroll 1
  for (int t = 0; t < 24; ++t){
    const int Q = P ^ 1;
    f32x4 xv = *(const f32x4*)&xlds[t * 16 + 4 * hi];

    // ---- layer 1 (reads a1 = h1T[P], preloaded) ----
    f32x4 gt[4];
#pragma unroll
    for (int j = 0; j < 4; ++j){
      f32x4 acc;
#pragma unroll
      for (int r = 0; r < 4; ++r) acc[r] = fmaf(xv[r], wiv[j], b1v[j]);
      acc = __builtin_amdgcn_mfma_f32_16x16x32_bf16(a1[0], fr1[j][0], acc, 0, 0, 0);
      acc = __builtin_amdgcn_mfma_f32_16x16x32_bf16(a1[1], fr1[j][1], acc, 0, 0, 0);
      gt[j] = acc;
    }
    float h1l[4], h1t[4];
#pragma unroll
    for (int r = 0; r < 4; ++r){
      float ti = fsig(gt[0][r]);
      float tf = fsig(gt[1][r]);
      float tg = ftanh(gt[2][r]);
      float to = fsig(gt[3][r]);
      float cn = fmaf(tf, c1r[r], ti * tg);
      c1r[r] = cn;
      h1l[r] = to * ftanh(cn) * ml1r[r];
      h1t[r] = h1l[r] * mt1r[r];
    }
    PK_STORE4(sh1L[Q], wIdx, h1l[0], h1l[1], h1l[2], h1l[3]);
    PK_STORE4(sh1T[Q], wIdx, h1t[0], h1t[1], h1t[2], h1t[3]);

    __syncthreads();   // the ONLY barrier per step

    short8v a2[2];
    a2[0]  = *(const short8v*)&sh1L[Q][rIdx[0]];
    a2[1]  = *(const short8v*)&sh1L[Q][rIdx[1]];
    a1[0]  = *(const short8v*)&sh1T[Q][rIdx[0]];   // next step's layer-1 input
    a1[1]  = *(const short8v*)&sh1T[Q][rIdx[1]];
    at2[0] = *(const short8v*)&sh2T[P][rIdx[0]];   // h2T written at t-1 (or init)
    at2[1] = *(const short8v*)&sh2T[P][rIdx[1]];

    // ---- layer 2 ----
#pragma unroll
    for (int j = 0; j < 4; ++j){
      f32x4 acc;
#pragma unroll
      for (int r = 0; r < 4; ++r) acc[r] = b2v[j];
      acc = __builtin_amdgcn_mfma_f32_16x16x32_bf16(a2[0],  frI[j][0], acc, 0, 0, 0);
      acc = __builtin_amdgcn_mfma_f32_16x16x32_bf16(a2[1],  frI[j][1], acc, 0, 0, 0);
      acc = __builtin_amdgcn_mfma_f32_16x16x32_bf16(at2[0], frH[j][0], acc, 0, 0, 0);
      acc = __builtin_amdgcn_mfma_f32_16x16x32_bf16(at2[1], frH[j][1], acc, 0, 0, 0);
      gt[j] = acc;
    }
    float h2t[4];
#pragma unroll
    for (int r = 0; r < 4; ++r){
      float ti = fsig(gt[0][r]);
      float tf = fsig(gt[1][r]);
      float tg = ftanh(gt[2][r]);
      float to = fsig(gt[3][r]);
      float cn = fmaf(tf, c2r[r], ti * tg);
      c2r[r] = cn;
      float h2l = to * ftanh(cn) * ml2r[r];
      h2t[r] = h2l * mt2r[r];
      if (t == 23) h2f[(4 * hi + r) * 64 + u] = h2l;
    }
    PK_STORE4(sh2T[Q], wIdx, h2t[0], h2t[1], h2t[2], h2t[3]);  // post-barrier write

    P = Q;
  }
  __syncthreads();   // h2f visible to reducer

  // ---- output: out[row][o] = sum_u h2f[row][u]*Wout[o][u] + bout[o] ----
  if (tid < 32){
    int r = tid & 15, o = tid >> 4;
    float acc = bout[o];
#pragma unroll 8
    for (int uu = 0; uu < 64; ++uu)
      acc = fmaf(h2f[r * 64 + uu], Wout[o * 64 + uu], acc);
    out[(row0 + r) * 2 + o] = acc;
  }
}

extern "C" void kernel_launch(void* const* d_in, const int* in_sizes, int n_in,
                              void* d_out, int out_size, void* d_ws, size_t ws_size,
                              hipStream_t stream)
{
  vlstm_kernel<<<dim3(4096), dim3(256), 0, stream>>>(
      (const float*)d_in[0],  (const float*)d_in[1],  (const float*)d_in[2],
      (const float*)d_in[3],  (const float*)d_in[4],  (const float*)d_in[5],
      (const float*)d_in[6],  (const float*)d_in[7],  (const float*)d_in[8],
      (const float*)d_in[9],  (const float*)d_in[10], (const float*)d_in[11],
      (const float*)d_in[12], (const float*)d_in[13], (const float*)d_in[14],
      (const float*)d_in[15], (const float*)d_in[16], (const float*)d_in[17],
      (const float*)d_in[18], (float*)d_out);
}

// Round 5
// 351.394 us; speedup vs baseline: 3.2282x; 2.3964x over previous
//
#include <hip/hip_runtime.h>

// VariationalLSTM: B=65536, T=24, H=64. 4096 WGs x 256 thr (4 waves); each WG owns
// ONE 16-row batch tile for all 24 steps. Wave w owns gate units u = 16w + (lane&15).
// LDS layout (R1-proven): bf16 tiles [16 rows m][64 units u], XOR swizzle
// byte ^= (m&7)<<4; A-frags via ds_read_b128, k-map f(kk,hi,e)=32kk+8hi+e shared
// by A and B. Double-buffered tiles -> ONE barrier per timestep. cvt_pk stores.
//
// __launch_bounds__(256,2): allocator behaves like R1 (no arch/AGPR split, no
// spill, ~132 total regs) -> hardware fits 3 WGs/CU at runtime with the 4096 grid.
// ((256,3)/(256,4) make the compiler split the unified file 50/50 arch/AGPR and
// spill the 96 weight VGPRs -> 1-4 GB scratch traffic; R3/R4 post-mortems.)
//
// Activation prescale folded into weights: i,f,o rows of W/b scaled by -log2e
// (sigmoid = rcp(1+exp2(y))); g rows scaled by +2*log2e (tanh = 1-2*rcp(1+exp2(y))).

typedef short short8v __attribute__((ext_vector_type(8)));
typedef float f32x4 __attribute__((ext_vector_type(4)));

#define LOG2E 1.44269504088896340736f

__device__ inline float gsig(float y){      // sigmoid of prescaled gate (y = -log2e*x)
  return __builtin_amdgcn_rcpf(1.0f + __builtin_amdgcn_exp2f(y));
}
__device__ inline float gtanh(float y){     // tanh of prescaled gate (y = 2*log2e*x)
  float s = __builtin_amdgcn_rcpf(1.0f + __builtin_amdgcn_exp2f(y));
  return fmaf(-2.0f, s, 1.0f);
}
__device__ inline float ftanh(float x){     // tanh of fp32 value (cell state)
  float e = __builtin_amdgcn_exp2f((2.0f * LOG2E) * x);
  return fmaf(-2.0f, __builtin_amdgcn_rcpf(1.0f + e), 1.0f);
}
__device__ inline unsigned short bf16c(float f){  // RNE f32->bf16 (weight init only)
  unsigned uu = __builtin_bit_cast(unsigned, f);
  uu = (uu + 0x7fffu + ((uu >> 16) & 1u)) >> 16;
  return (unsigned short)uu;
}

// 4 rows (same unit column u) -> 2x v_cvt_pk_bf16_f32 (D.lo=S0 per T12) + 4x b16.
#define PK_STORE4(T, I, f0, f1, f2, f3) do{                       \
    unsigned _w01, _w23;                                          \
    asm("v_cvt_pk_bf16_f32 %0, %1, %2" : "=v"(_w01) : "v"(f0), "v"(f1)); \
    asm("v_cvt_pk_bf16_f32 %0, %1, %2" : "=v"(_w23) : "v"(f2), "v"(f3)); \
    (T)[(I)[0]] = (unsigned short)_w01;                           \
    (T)[(I)[1]] = (unsigned short)(_w01 >> 16);                   \
    (T)[(I)[2]] = (unsigned short)_w23;                           \
    (T)[(I)[3]] = (unsigned short)(_w23 >> 16);                   \
  }while(0)

__global__ __launch_bounds__(256, 2) void vlstm_kernel(
    const float* __restrict__ x,
    const float* __restrict__ Wih1, const float* __restrict__ Whh1,
    const float* __restrict__ bih1, const float* __restrict__ bhh1,
    const float* __restrict__ Wih2, const float* __restrict__ Whh2,
    const float* __restrict__ bih2, const float* __restrict__ bhh2,
    const float* __restrict__ Wout, const float* __restrict__ bout,
    const float* __restrict__ h10, const float* __restrict__ c10,
    const float* __restrict__ h20, const float* __restrict__ c20,
    const float* __restrict__ mt1v, const float* __restrict__ mt2v,
    const float* __restrict__ ml1v, const float* __restrict__ ml2v,
    float* __restrict__ out)
{
  __shared__ unsigned short sh1L[2][1024];  // h1*m_layer1           (layer2 input)
  __shared__ unsigned short sh1T[2][1024];  // h1*m_layer1*m_time1   (next-step L1 h)
  __shared__ unsigned short sh2T[2][1024];  // h2*m_layer2*m_time2   (next-step L2 h)
  __shared__ float h2f[1024];               // final h2 (fp32)
  __shared__ float xlds[384];               // x transposed [24][16]

  const int tid = threadIdx.x;
  const int w  = tid >> 6;
  const int l  = tid & 63;
  const int hi = l >> 4;
  const int lo = l & 15;
  const int u  = 16 * w + lo;               // gate unit owned (D col = lane&15)

  // ---- one-time: prescaled biases/x-coeffs/weight B-frags (k-map 32kk+8hi+e) ----
  // gate j: 0=i, 1=f, 2=g, 3=o.  scale = -LOG2E for i,f,o; +2*LOG2E for g.
  float b1v[4], b2v[4], wiv[4];
  short8v fr1[4][2], frI[4][2], frH[4][2];
#pragma unroll
  for (int j = 0; j < 4; ++j){
    const float sc = (j == 2) ? (2.0f * LOG2E) : (-LOG2E);
    int n = u + 64 * j;
    b1v[j] = sc * (bih1[n] + bhh1[n]);
    b2v[j] = sc * (bih2[n] + bhh2[n]);
    wiv[j] = sc * Wih1[n];
#pragma unroll
    for (int kk = 0; kk < 2; ++kk){
      int off = n * 64 + 32 * kk + 8 * hi;
      short8v s;
#pragma unroll
      for (int e = 0; e < 8; ++e) s[e] = (short)bf16c(sc * Whh1[off + e]);
      fr1[j][kk] = s;
#pragma unroll
      for (int e = 0; e < 8; ++e) s[e] = (short)bf16c(sc * Wih2[off + e]);
      frI[j][kk] = s;
#pragma unroll
      for (int e = 0; e < 8; ++e) s[e] = (short)bf16c(sc * Whh2[off + e]);
      frH[j][kk] = s;
    }
  }

  // ---- swizzled LDS offsets (ushort indices), byte ^= (m&7)<<4 ----
  int wIdx[4];                 // writes: rows m = 4hi+r, col u
#pragma unroll
  for (int r = 0; r < 4; ++r){
    int m = 4 * hi + r;
    wIdx[r] = ((m * 128 + u * 2) ^ ((m & 7) << 4)) >> 1;
  }
  int rIdx[2];                 // A-frag b128 reads: m = lo, k = 32kk + 8hi + e
#pragma unroll
  for (int kk = 0; kk < 2; ++kk){
    rIdx[kk] = ((lo * 128 + kk * 64 + hi * 16) ^ ((lo & 7) << 4)) >> 1;
  }

  const int row0 = blockIdx.x * 16;

  for (int idx = tid; idx < 384; idx += 256){
    int r = idx / 24, tt = idx - r * 24;
    xlds[tt * 16 + r] = x[(row0 + r) * 24 + tt];
  }
  float c1r[4], c2r[4], ml1r[4], ml2r[4], mt1r[4], mt2r[4];
  float h1i[4], h2i[4];
#pragma unroll
  for (int r = 0; r < 4; ++r){
    int gofs = (row0 + 4 * hi + r) * 64 + u;
    c1r[r]  = c10[gofs];  c2r[r]  = c20[gofs];
    ml1r[r] = ml1v[gofs]; ml2r[r] = ml2v[gofs];
    mt1r[r] = mt1v[gofs]; mt2r[r] = mt2v[gofs];
    h1i[r] = h10[gofs] * mt1r[r];
    h2i[r] = h20[gofs] * mt2r[r];
  }
  PK_STORE4(sh1T[0], wIdx, h1i[0], h1i[1], h1i[2], h1i[3]);
  PK_STORE4(sh2T[0], wIdx, h2i[0], h2i[1], h2i[2], h2i[3]);
  __syncthreads();

  short8v a1[2], at2[2];
  a1[0] = *(const short8v*)&sh1T[0][rIdx[0]];
  a1[1] = *(const short8v*)&sh1T[0][rIdx[1]];

  int P = 0;
#pragma unroll 1
  for (int t = 0; t < 24; ++t){
    const int Q = P ^ 1;
    f32x4 xv = *(const f32x4*)&xlds[t * 16 + 4 * hi];

    // ---- layer 1 (reads a1 = h1T[P], preloaded) ----
    f32x4 gt[4];
#pragma unroll
    for (int j = 0; j < 4; ++j){
      f32x4 acc;
#pragma unroll
      for (int r = 0; r < 4; ++r) acc[r] = fmaf(xv[r], wiv[j], b1v[j]);
      acc = __builtin_amdgcn_mfma_f32_16x16x32_bf16(a1[0], fr1[j][0], acc, 0, 0, 0);
      acc = __builtin_amdgcn_mfma_f32_16x16x32_bf16(a1[1], fr1[j][1], acc, 0, 0, 0);
      gt[j] = acc;
    }
    float h1l[4], h1t[4];
#pragma unroll
    for (int r = 0; r < 4; ++r){
      float ti = gsig(gt[0][r]);
      float tf = gsig(gt[1][r]);
      float tg = gtanh(gt[2][r]);
      float to = gsig(gt[3][r]);
      float cn = fmaf(tf, c1r[r], ti * tg);
      c1r[r] = cn;
      h1l[r] = to * ftanh(cn) * ml1r[r];
      h1t[r] = h1l[r] * mt1r[r];
    }
    PK_STORE4(sh1L[Q], wIdx, h1l[0], h1l[1], h1l[2], h1l[3]);
    PK_STORE4(sh1T[Q], wIdx, h1t[0], h1t[1], h1t[2], h1t[3]);

    __syncthreads();   // the ONLY barrier per step

    short8v a2[2];
    a2[0]  = *(const short8v*)&sh1L[Q][rIdx[0]];
    a2[1]  = *(const short8v*)&sh1L[Q][rIdx[1]];
    a1[0]  = *(const short8v*)&sh1T[Q][rIdx[0]];   // next step's layer-1 input
    a1[1]  = *(const short8v*)&sh1T[Q][rIdx[1]];
    at2[0] = *(const short8v*)&sh2T[P][rIdx[0]];   // h2T written at t-1 (or init)
    at2[1] = *(const short8v*)&sh2T[P][rIdx[1]];

    // ---- layer 2 ----
#pragma unroll
    for (int j = 0; j < 4; ++j){
      f32x4 acc;
#pragma unroll
      for (int r = 0; r < 4; ++r) acc[r] = b2v[j];
      acc = __builtin_amdgcn_mfma_f32_16x16x32_bf16(a2[0],  frI[j][0], acc, 0, 0, 0);
      acc = __builtin_amdgcn_mfma_f32_16x16x32_bf16(a2[1],  frI[j][1], acc, 0, 0, 0);
      acc = __builtin_amdgcn_mfma_f32_16x16x32_bf16(at2[0], frH[j][0], acc, 0, 0, 0);
      acc = __builtin_amdgcn_mfma_f32_16x16x32_bf16(at2[1], frH[j][1], acc, 0, 0, 0);
      gt[j] = acc;
    }
    float h2t[4];
#pragma unroll
    for (int r = 0; r < 4; ++r){
      float ti = gsig(gt[0][r]);
      float tf = gsig(gt[1][r]);
      float tg = gtanh(gt[2][r]);
      float to = gsig(gt[3][r]);
      float cn = fmaf(tf, c2r[r], ti * tg);
      c2r[r] = cn;
      float h2l = to * ftanh(cn) * ml2r[r];
      h2t[r] = h2l * mt2r[r];
      if (t == 23) h2f[(4 * hi + r) * 64 + u] = h2l;
    }
    PK_STORE4(sh2T[Q], wIdx, h2t[0], h2t[1], h2t[2], h2t[3]);  // post-barrier write

    P = Q;
  }
  __syncthreads();   // h2f visible to reducer

  // ---- output: out[row][o] = sum_u h2f[row][u]*Wout[o][u] + bout[o] ----
  if (tid < 32){
    int r = tid & 15, o = tid >> 4;
    float acc = bout[o];
#pragma unroll 8
    for (int uu = 0; uu < 64; ++uu)
      acc = fmaf(h2f[r * 64 + uu], Wout[o * 64 + uu], acc);
    out[(row0 + r) * 2 + o] = acc;
  }
}

extern "C" void kernel_launch(void* const* d_in, const int* in_sizes, int n_in,
                              void* d_out, int out_size, void* d_ws, size_t ws_size,
                              hipStream_t stream)
{
  vlstm_kernel<<<dim3(4096), dim3(256), 0, stream>>>(
      (const float*)d_in[0],  (const float*)d_in[1],  (const float*)d_in[2],
      (const float*)d_in[3],  (const float*)d_in[4],  (const float*)d_in[5],
      (const float*)d_in[6],  (const float*)d_in[7],  (const float*)d_in[8],
      (const float*)d_in[9],  (const float*)d_in[10], (const float*)d_in[11],
      (const float*)d_in[12], (const float*)d_in[13], (const float*)d_in[14],
      (const float*)d_in[15], (const float*)d_in[16], (const float*)d_in[17],
      (const float*)d_in[18], (float*)d_out);
}